// Round 1
// baseline (43.445 us; speedup 1.0000x reference)
//
#include <hip/hip_runtime.h>

// Rewavelet: in (8,256,256,64) f32 NHWC -> out (8,512,512,16) f32 NHWC
// out[b, 2h+sh, 2w+sw, gi] = a + sb*b + s_h*(c + sb*d),
//   a..d = in[b,h,w,4gi..4gi+3], sb = (sw==0? +1:-1), s_h = (sh==0? +1:-1)
//
// One thread per (pixel, gi4): gi4 in [0,4) covers groups 4*gi4..4*gi4+3.
// Reads 4 consecutive float4 (64B), writes 4 float4 to the four (sh,sw) pixels.

#define HAAR4(v, S00, S01, S10, S11)                                          \
    {                                                                         \
        float t0 = (v).x + (v).y, t1 = (v).x - (v).y;                         \
        float t2 = (v).z + (v).w, t3 = (v).z - (v).w;                         \
        (S00) = t0 + t2; (S01) = t1 + t3; (S10) = t0 - t2; (S11) = t1 - t3;   \
    }

__global__ void __launch_bounds__(256) rewavelet_kernel(
    const float4* __restrict__ in, float4* __restrict__ out)
{
    int tid = blockIdx.x * 256 + threadIdx.x;   // 0 .. 2M-1
    int gi4 = tid & 3;                          // which quarter of the 16 groups
    int pix = tid >> 2;                         // b*65536 + h*256 + w
    int w   = pix & 255;
    int h   = (pix >> 8) & 255;
    int b   = pix >> 16;

    // input: pixel base = pix*16 float4s; this thread reads float4s [gi4*4, gi4*4+4)
    const float4* ip = in + (((size_t)pix) << 4) + (gi4 << 2);
    float4 v0 = ip[0];
    float4 v1 = ip[1];
    float4 v2 = ip[2];
    float4 v3 = ip[3];

    float4 s00, s01, s10, s11;
    HAAR4(v0, s00.x, s01.x, s10.x, s11.x);
    HAAR4(v1, s00.y, s01.y, s10.y, s11.y);
    HAAR4(v2, s00.z, s01.z, s10.z, s11.z);
    HAAR4(v3, s00.w, s01.w, s10.w, s11.w);

    // output float4 index: ((b*512 + hh)*512 + ww)*4 + gi4   (16 floats = 4 float4 per pixel)
    size_t o = ((((size_t)b * 512 + 2 * h) * 512) + 2 * w) * 4 + gi4;
    out[o]        = s00;   // (2h,   2w)
    out[o + 4]    = s01;   // (2h,   2w+1)
    out[o + 2048] = s10;   // (2h+1, 2w)   row stride = 512*4 float4
    out[o + 2052] = s11;   // (2h+1, 2w+1)
}

extern "C" void kernel_launch(void* const* d_in, const int* in_sizes, int n_in,
                              void* d_out, int out_size, void* d_ws, size_t ws_size,
                              hipStream_t stream)
{
    const float4* in = (const float4*)d_in[0];
    float4* out      = (float4*)d_out;

    const int total_threads = 8 * 256 * 256 * 4;   // 2,097,152
    const int block = 256;
    const int grid  = total_threads / block;       // 8192
    rewavelet_kernel<<<grid, block, 0, stream>>>(in, out);
}